// Round 14
// baseline (248.424 us; speedup 1.0000x reference)
//
#include <hip/hip_runtime.h>

#define NN 100000
#define EE 1600000
#define HN 128
#define OO 64
#define SB 256     // stats blocks
#define NBUCK 196  // ceil(NN/512), bucket = row >> 9
#define CH 4096    // edges per bucketing chunk
#define SLAB 16384 // fixed slab per bucket (mean 8192; overflow ~90 sigma -> nil)

typedef __attribute__((ext_vector_type(8))) short bf16x8;
typedef __attribute__((ext_vector_type(4))) float f32x4;

__device__ __forceinline__ unsigned short f2bf(float f){ // RNE bf16
  unsigned u = __float_as_uint(f);
  return (unsigned short)((u + 0x7FFFu + ((u >> 16) & 1u)) >> 16);
}
__device__ __forceinline__ float bflo(unsigned u){ return __uint_as_float(u << 16); }
__device__ __forceinline__ float bfhi(unsigned u){ return __uint_as_float(u & 0xFFFF0000u); }

#define CB ((EE + CH - 1)/CH)   // 391 bucket blocks
#define GB ((NN + 127)/128)     // 782 gemm blocks

// ---------------- fused: bucket-scatter (+W2/W3 pack) || mgemm1 (h1 = bf16(x@W1), UNSCALED) ----------------
__global__ __launch_bounds__(256) void k_fused(const int* __restrict__ rows, const int* __restrict__ cols,
                                               int* __restrict__ pcur, unsigned* __restrict__ ebuf,
                                               const float* __restrict__ x, const float* __restrict__ W1,
                                               const float* __restrict__ W2, const float* __restrict__ W3,
                                               unsigned short* __restrict__ Wp2, unsigned short* __restrict__ Wp3,
                                               unsigned* __restrict__ hbf){
  __shared__ char lds[65536];
  const int t = threadIdx.x;

  if (blockIdx.x < CB){
    // ================= bucket path =================
    int* bc    = (int*)lds;            // [256]
    int* boff  = (int*)(lds + 1024);
    int* ccur  = (int*)(lds + 2048);
    int* gbase = (int*)(lds + 3072);
    uint2* stage = (uint2*)(lds + 4096);  // 32 KB
    const int base = blockIdx.x * CH;
    const int nval = min(CH, EE - base);

    for (int i = t; i < NBUCK; i += 256) bc[i] = 0;
    __syncthreads();

    int er[16], ec[16];
    #pragma unroll
    for (int j = 0; j < 16; ++j){
      int i = j*256 + t;
      if (i < nval){
        er[j] = rows[base+i]; ec[j] = cols[base+i];
        atomicAdd(&bc[er[j] >> 9], 1);
      } else er[j] = -1;
    }
    __syncthreads();

    if (t < 64){ // wave-0 scan of bc -> boff
      int lane = t, run = 0;
      for (int c = 0; c < NBUCK; c += 64){
        int i = c + lane;
        int v = (i < NBUCK) ? bc[i] : 0;
        int s = v;
        #pragma unroll
        for (int d = 1; d < 64; d <<= 1){ int u = __shfl_up(s, d); if (lane >= d) s += u; }
        if (i < NBUCK) boff[i] = run + s - v;
        run += __shfl(s, 63);
      }
    }
    __syncthreads();
    if (t < NBUCK){
      gbase[t] = bc[t] ? (t*SLAB + atomicAdd(&pcur[t], bc[t])) : 0;
      ccur[t]  = boff[t];
    }
    __syncthreads();
    #pragma unroll
    for (int j = 0; j < 16; ++j){
      if (er[j] >= 0){
        int b = er[j] >> 9;
        int p = atomicAdd(&ccur[b], 1);
        stage[p] = make_uint2((unsigned)er[j], (unsigned)ec[j]);
      }
    }
    __syncthreads();
    for (int i = t; i < nval; i += 256){
      uint2 e = stage[i];
      int b = (int)(e.x >> 9);
      unsigned pk = ((e.x & 511u) << 17) | e.y;   // packed: lrow(9b) | col(17b)
      ebuf[gbase[b] + (i - boff[b])] = pk;
    }

    // W2/W3 pack on blocks 0..11 (consumed by later dispatches)
    int b = blockIdx.x;
    if (b < 12){
      const float* W = (b < 8) ? W2 : W3;
      unsigned short* Wp = (b < 8) ? Wp2 : Wp3;
      int outc = (b < 8) ? 128 : 64;
      int i0 = (b < 8) ? b*256 : (b-8)*256;
      int i = i0 + t;
      if (i < 16*outc){
        int kb = i / outc, n = i - kb*outc;
        unsigned pk[4];
        #pragma unroll
        for (int jj = 0; jj < 4; ++jj){
          unsigned lo = f2bf(W[(size_t)(kb*8 + 2*jj)*outc + n]);
          unsigned hi = f2bf(W[(size_t)(kb*8 + 2*jj+1)*outc + n]);
          pk[jj] = lo | (hi << 16);
        }
        *reinterpret_cast<uint4*>(Wp + (size_t)i*8) = make_uint4(pk[0],pk[1],pk[2],pk[3]);
      }
    }
  } else {
    // ================= mgemm1 path: h1 = bf16(x @ W1), unscaled =================
    char* AsB = lds;            // 32 KB A tile
    char* WsB = lds + 32768;    // 32 KB W tile [kb][n][8]
    const int row0 = (int)(blockIdx.x - CB) * 128;

    { // stage W1 fp32 -> bf16 packed (L2-hot after first block)
      #pragma unroll
      for (int it = 0; it < 8; ++it){
        int i = it*256 + t;            // 0..2047
        int kb = i >> 7, n = i & 127;
        unsigned pk[4];
        #pragma unroll
        for (int j = 0; j < 4; ++j){
          unsigned lo = f2bf(W1[(size_t)(kb*8 + 2*j)*128 + n]);
          unsigned hi = f2bf(W1[(size_t)(kb*8 + 2*j+1)*128 + n]);
          pk[j] = lo | (hi << 16);
        }
        *reinterpret_cast<uint4*>(WsB + (size_t)i*16) = make_uint4(pk[0],pk[1],pk[2],pk[3]);
      }
    }
    { // stage A (fp32 x) -> bf16 swizzled
      #pragma unroll
      for (int g = 0; g < 16; ++g){
        int f = g*256 + t;
        int r = f >> 5;
        int c4 = f & 31;
        int row = row0 + r;
        int rc = row < NN ? row : NN-1;
        float4 v = *reinterpret_cast<const float4*>(x + (size_t)rc*HN + c4*4);
        unsigned p0 = (unsigned)f2bf(v.x) | ((unsigned)f2bf(v.y) << 16);
        unsigned p1 = (unsigned)f2bf(v.z) | ((unsigned)f2bf(v.w) << 16);
        int boffb = (c4*8) ^ ((r & 7) << 4);
        *reinterpret_cast<uint2*>(AsB + r*256 + boffb) = make_uint2(p0, p1);
      }
    }
    __syncthreads();

    const int wv = t >> 6;
    const int l  = t & 63;
    const int lm = l & 15;
    const int lk = l >> 4;

    f32x4 acc[2][8];
    #pragma unroll
    for (int mi=0;mi<2;++mi)
      #pragma unroll
      for (int ni=0;ni<8;++ni) acc[mi][ni] = (f32x4){0.f,0.f,0.f,0.f};

    #pragma unroll
    for (int ks = 0; ks < 4; ++ks){
      bf16x8 af[2];
      #pragma unroll
      for (int mi=0;mi<2;++mi){
        int R = wv*32 + mi*16 + lm;
        int boffb = (ks*64 + lk*16) ^ ((R & 7) << 4);
        af[mi] = *reinterpret_cast<const bf16x8*>(AsB + R*256 + boffb);
      }
      int kb = ks*4 + lk;
      #pragma unroll
      for (int ni=0;ni<8;++ni){
        int n = ni*16 + lm;
        bf16x8 bfr = *reinterpret_cast<const bf16x8*>(WsB + (size_t)(kb*128 + n)*16);
        acc[0][ni] = __builtin_amdgcn_mfma_f32_16x16x32_bf16(af[0], bfr, acc[0][ni], 0,0,0);
        acc[1][ni] = __builtin_amdgcn_mfma_f32_16x16x32_bf16(af[1], bfr, acc[1][ni], 0,0,0);
      }
    }

    #pragma unroll
    for (int mi=0;mi<2;++mi){
      #pragma unroll
      for (int j=0;j<4;++j){
        int grow = row0 + wv*32 + mi*16 + lk*4 + j;
        if (grow >= NN) continue;
        unsigned short* po = (unsigned short*)hbf + (size_t)grow*HN;
        #pragma unroll
        for (int ni=0;ni<8;++ni)
          po[ni*16 + lm] = f2bf(acc[mi][ni][j]);   // UNSCALED
      }
    }
  }
}

// ---------------- per-bucket CSR finalize (slab, packed) ----------------
__global__ __launch_bounds__(256) void k_build(const unsigned* __restrict__ ebuf,
                                               const int* __restrict__ pcur,
                                               int* __restrict__ row_start, int* __restrict__ cnt,
                                               float* __restrict__ dinv, int* __restrict__ csr_col){
  __shared__ int hist[512];
  __shared__ int cur[512];
  __shared__ int sCbase;
  const int b = blockIdx.x;
  const int row0 = b << 9;
  const int nrow = min(512, NN - row0);
  const int ebase = b * SLAB;
  const int ne = pcur[b];
  const int t = threadIdx.x;

  if (t < 64){ // csr base = sum pcur[0..b)
    int acc = 0;
    for (int i = t; i < b; i += 64) acc += pcur[i];
    #pragma unroll
    for (int d = 32; d; d >>= 1) acc += __shfl_xor(acc, d);
    if (t == 0) sCbase = acc;
  }
  for (int i = t; i < nrow; i += 256) hist[i] = 0;
  __syncthreads();
  for (int i = t; i < ne; i += 256)
    atomicAdd(&hist[ebuf[ebase+i] >> 17], 1);
  __syncthreads();

  if (t < 64){
    int lane = t, run = 0;
    for (int c = 0; c < nrow; c += 64){
      int i = c + lane;
      int v = (i < nrow) ? hist[i] : 0;
      int s = v;
      #pragma unroll
      for (int d = 1; d < 64; d <<= 1){ int u = __shfl_up(s, d); if (lane >= d) s += u; }
      if (i < nrow) cur[i] = run + s - v;
      run += __shfl(s, 63);
    }
  }
  __syncthreads();
  const int cbase = sCbase;
  for (int i = t; i < nrow; i += 256){
    int h = hist[i];
    int r = row0 + i;
    cnt[r] = h;
    dinv[r] = rsqrtf((float)(h+1));
    row_start[r] = cbase + cur[i];
    cur[i] += cbase;
  }
  __syncthreads();
  for (int i = t; i < ne; i += 256){
    unsigned e = ebuf[ebase+i];
    int p = atomicAdd(&cur[e >> 17], 1);
    csr_col[p] = (int)(e & 0x1FFFFu);
  }
}

// ---------------- agg layer 1: dinv-weighted gather over UNSCALED bf16 h ----------------
__global__ __launch_bounds__(256) void k_aggd(const unsigned* __restrict__ h,
                                              const int* __restrict__ row_start,
                                              const int* __restrict__ cnt,
                                              const int* __restrict__ col,
                                              const float* __restrict__ dinv,
                                              const float* __restrict__ bias,
                                              unsigned* __restrict__ outv){
  int wib  = __builtin_amdgcn_readfirstlane((int)(threadIdx.x >> 6));
  int wid  = blockIdx.x*4 + wib;
  int lane = threadIdx.x & 63;
  if (wid >= NN) return;
  int s = row_start[wid];
  int e = s + cnt[wid];
  float dr = dinv[wid];
  const unsigned* hp = h + lane;
  float ax, ay;
  {
    unsigned u = hp[(size_t)wid*64];
    ax = dr*bflo(u); ay = dr*bfhi(u);
  }
  int p = s;
  for (; p+7 < e; p += 8){
    unsigned uu[8]; float dd[8];
    #pragma unroll
    for (int j=0;j<8;++j){ int c = col[p+j]; dd[j] = dinv[c]; uu[j] = hp[(size_t)c*64]; }
    #pragma unroll
    for (int j=0;j<8;++j){ ax = fmaf(bflo(uu[j]), dd[j], ax); ay = fmaf(bfhi(uu[j]), dd[j], ay); }
  }
  for (; p+3 < e; p += 4){
    unsigned uu[4]; float dd[4];
    #pragma unroll
    for (int j=0;j<4;++j){ int c = col[p+j]; dd[j] = dinv[c]; uu[j] = hp[(size_t)c*64]; }
    #pragma unroll
    for (int j=0;j<4;++j){ ax = fmaf(bflo(uu[j]), dd[j], ax); ay = fmaf(bfhi(uu[j]), dd[j], ay); }
  }
  for (; p < e; ++p){
    int c = col[p]; float d = dinv[c];
    unsigned u = hp[(size_t)c*64];
    ax = fmaf(bflo(u), d, ax); ay = fmaf(bfhi(u), d, ay);
  }
  float2 bb = *reinterpret_cast<const float2*>(bias + 2*lane);
  float ox = ax*dr + bb.x, oy = ay*dr + bb.y;
  outv[(size_t)wid*64 + lane] = (unsigned)f2bf(ox) | ((unsigned)f2bf(oy) << 16);
}

// ---------------- fused BN stats + finalize (all-atomic cross-block protocol) ----------------
__global__ __launch_bounds__(256) void k_statsfin(const unsigned* __restrict__ a,
                                                  float* __restrict__ gps, float* __restrict__ gpq,
                                                  int* __restrict__ done,
                                                  const float* __restrict__ gamma, const float* __restrict__ beta,
                                                  float* __restrict__ scale, float* __restrict__ shiftv){
  __shared__ float l0[256], l1[256], m0[256], m1[256];
  __shared__ int lastFlag;
  int c = threadIdx.x & 63;
  int grp = threadIdx.x >> 6;
  float s0=0.f,s1=0.f,q0=0.f,q1=0.f;
  for (int r = blockIdx.x*4 + grp; r < NN; r += SB*4){
    unsigned u = a[(size_t)r*64 + c];
    float v0 = bflo(u), v1 = bfhi(u);
    s0 += v0; s1 += v1; q0 = fmaf(v0,v0,q0); q1 = fmaf(v1,v1,q1);
  }
  l0[threadIdx.x]=s0; l1[threadIdx.x]=s1; m0[threadIdx.x]=q0; m1[threadIdx.x]=q1;
  __syncthreads();
  if (grp==0){
    #pragma unroll
    for (int g=1;g<4;++g){ s0+=l0[g*64+c]; s1+=l1[g*64+c]; q0+=m0[g*64+c]; q1+=m1[g*64+c]; }
    // device-scope atomic accumulation into 128-channel totals (coherent point)
    atomicAdd(&gps[2*c],   s0);
    atomicAdd(&gps[2*c+1], s1);
    atomicAdd(&gpq[2*c],   q0);
    atomicAdd(&gpq[2*c+1], q1);
  }
  __threadfence();
  if (threadIdx.x == 0) lastFlag = (atomicAdd(done, 1) == SB-1);
  __syncthreads();
  if (lastFlag && threadIdx.x < 128){
    int ch = threadIdx.x;
    float s = atomicAdd(&gps[ch], 0.0f);   // atomic read: device-coherent
    float q = atomicAdd(&gpq[ch], 0.0f);
    float mean = s * (1.0f/NN);
    float var  = q * (1.0f/NN) - mean*mean;
    float inv  = rsqrtf(var + 1e-5f);
    float sc = gamma[ch]*inv;
    scale[ch]  = sc;                       // plain store: next-dispatch boundary synchronizes
    shiftv[ch] = beta[ch] - mean*sc;
  }
}

// ---------------- fused: agg layer-2 (pre-scaled h2') + relu + GEMM3 + b3 -> out fp32 ----------------
// 16 rows/block: 4 waves x 4 rows (halved serial row chain); MFMA M=16,N=64 (wave wv owns n-block wv)
__global__ __launch_bounds__(256) void k_aggmm(const unsigned* __restrict__ h,
                                               const int* __restrict__ row_start,
                                               const int* __restrict__ cnt,
                                               const int* __restrict__ col,
                                               const float* __restrict__ dinv,
                                               const float* __restrict__ b2,
                                               const unsigned short* __restrict__ Wp3,
                                               const float* __restrict__ b3,
                                               float* __restrict__ out){
  __shared__ char AsB[16*256];   // 16 rows x 256 B bf16, XOR-swizzled
  const int t = threadIdx.x;
  const int wv = __builtin_amdgcn_readfirstlane(t >> 6);
  const int lane = t & 63;
  const int tile = blockIdx.x * 16;

  for (int k = 0; k < 4; ++k){
    int wid = tile + wv*4 + k;          // NN = 6250*16
    int s = row_start[wid];
    int e = s + cnt[wid];
    float dr = dinv[wid];
    const unsigned* hp = h + lane;
    float ax, ay;
    { unsigned u = hp[(size_t)wid*64]; ax = bflo(u); ay = bfhi(u); }
    int p = s;
    for (; p+7 < e; p += 8){
      unsigned uu[8];
      #pragma unroll
      for (int j=0;j<8;++j) uu[j] = hp[(size_t)col[p+j]*64];
      #pragma unroll
      for (int j=0;j<8;++j){ ax += bflo(uu[j]); ay += bfhi(uu[j]); }
    }
    for (; p+3 < e; p += 4){
      unsigned uu[4];
      #pragma unroll
      for (int j=0;j<4;++j) uu[j] = hp[(size_t)col[p+j]*64];
      #pragma unroll
      for (int j=0;j<4;++j){ ax += bflo(uu[j]); ay += bfhi(uu[j]); }
    }
    for (; p < e; ++p){
      unsigned u = hp[(size_t)col[p]*64];
      ax += bflo(u); ay += bfhi(u);
    }
    float2 bb = *reinterpret_cast<const float2*>(b2 + 2*lane);
    float ox = fmaxf(ax*dr + bb.x, 0.f);   // relu fused
    float oy = fmaxf(ay*dr + bb.y, 0.f);
    int r = wv*4 + k;
    unsigned pk = (unsigned)f2bf(ox) | ((unsigned)f2bf(oy) << 16);
    *reinterpret_cast<unsigned*>(AsB + r*256 + ((lane*4) ^ ((r & 7) << 4))) = pk;
  }
  __syncthreads();

  const int lm = lane & 15;
  const int lk = lane >> 4;
  f32x4 acc = (f32x4){0.f,0.f,0.f,0.f};
  const bf16x8* WpV = reinterpret_cast<const bf16x8*>(Wp3);

  #pragma unroll
  for (int ks = 0; ks < 4; ++ks){
    int R = lm;                         // A rows 0..15
    bf16x8 af = *reinterpret_cast<const bf16x8*>(AsB + R*256 + ((ks*64 + lk*16) ^ ((R & 7) << 4)));
    int kb = ks*4 + lk;
    bf16x8 bfr = WpV[kb*OO + wv*16 + lm];   // wave wv -> cols wv*16..+16
    acc = __builtin_amdgcn_mfma_f32_16x16x32_bf16(af, bfr, acc, 0,0,0);
  }

  int gcol = wv*16 + lm;
  float bb = b3[gcol];
  #pragma unroll
  for (int j = 0; j < 4; ++j){
    int grow = tile + lk*4 + j;
    out[(size_t)grow*OO + gcol] = acc[j] + bb;
  }
}

// ---------------- MFMA GEMM2: h2' = bf16(dinv * (BNrelu(abf) @ W2)) ----------------
__global__ __launch_bounds__(256) void k_mgemm2(const unsigned* __restrict__ Av,
                                                const unsigned short* __restrict__ Wp,
                                                const float* __restrict__ scale,
                                                const float* __restrict__ shiftv,
                                                const float* __restrict__ dinv,
                                                unsigned* __restrict__ Cv){
  __shared__ char AsB[32768];
  const int t = threadIdx.x;
  const int row0 = blockIdx.x * 128;

  { // stage bf16 A with BN+relu
    const uint4* A = (const uint4*)Av;   // 16 uint4 per row
    const int c8 = t & 15;
    const int k0 = c8*8;
    float sc[8], sh[8];
    #pragma unroll
    for (int j=0;j<8;++j){ sc[j]=scale[k0+j]; sh[j]=shiftv[k0+j]; }
    #pragma unroll
    for (int g = 0; g < 8; ++g){
      int f = g*256 + t;
      int r = f >> 4;
      int row = row0 + r;
      int rc = row < NN ? row : NN-1;
      uint4 q = A[(size_t)rc*16 + c8];
      float vf[8] = { bflo(q.x),bfhi(q.x),bflo(q.y),bfhi(q.y),
                      bflo(q.z),bfhi(q.z),bflo(q.w),bfhi(q.w) };
      #pragma unroll
      for (int j=0;j<8;++j) vf[j] = fmaxf(fmaf(vf[j], sc[j], sh[j]), 0.f);
      unsigned pk[4];
      #pragma unroll
      for (int j=0;j<4;++j)
        pk[j] = (unsigned)f2bf(vf[2*j]) | ((unsigned)f2bf(vf[2*j+1]) << 16);
      int boffb = (c8*16) ^ ((r & 7) << 4);
      *reinterpret_cast<uint4*>(AsB + r*256 + boffb) = make_uint4(pk[0],pk[1],pk[2],pk[3]);
    }
  }
  __syncthreads();

  const int wv = t >> 6;
  const int l  = t & 63;
  const int lm = l & 15;
  const int lk = l >> 4;

  f32x4 acc[2][8];
  #pragma unroll
  for (int mi=0;mi<2;++mi)
    #pragma unroll
    for (int ni=0;ni<8;++ni) acc[mi][ni] = (f32x4){0.f,0.f,0.f,0.f};

  const bf16x8* WpV = reinterpret_cast<const bf16x8*>(Wp);

  #pragma unroll
  for (int ks = 0; ks < 4; ++ks){
    bf16x8 af[2];
    #pragma unroll
    for (int mi=0;mi<2;++mi){
      int R = wv*32 + mi*16 + lm;
      int boffb = (ks*64 + lk*16) ^ ((R & 7) << 4);
      af[mi] = *reinterpret_cast<const bf16x8*>(AsB + R*256 + boffb);
    }
    int kb = ks*4 + lk;
    #pragma unroll
    for (int ni=0;ni<8;++ni){
      int n = ni*16 + lm;
      bf16x8 bfr = WpV[kb*128 + n];
      acc[0][ni] = __builtin_amdgcn_mfma_f32_16x16x32_bf16(af[0], bfr, acc[0][ni], 0,0,0);
      acc[1][ni] = __builtin_amdgcn_mfma_f32_16x16x32_bf16(af[1], bfr, acc[1][ni], 0,0,0);
    }
  }

  #pragma unroll
  for (int mi=0;mi<2;++mi){
    #pragma unroll
    for (int j=0;j<4;++j){
      int grow = row0 + wv*32 + mi*16 + lk*4 + j;
      if (grow >= NN) continue;
      float dr = dinv[grow];
      unsigned short* po = (unsigned short*)Cv + (size_t)grow*HN;
      #pragma unroll
      for (int ni=0;ni<8;++ni)
        po[ni*16 + lm] = f2bf(acc[mi][ni][j] * dr);
    }
  }
}

// ---------------- launch ----------------
extern "C" void kernel_launch(void* const* d_in, const int* in_sizes, int n_in,
                              void* d_out, int out_size, void* d_ws, size_t ws_size,
                              hipStream_t stream) {
  const float* x      = (const float*)d_in[0];
  const int*   ei     = (const int*)d_in[1];
  const int*   rows   = ei;
  const int*   cols   = ei + EE;
  const float* W1     = (const float*)d_in[2];
  const float* b1     = (const float*)d_in[3];
  const float* gamma1 = (const float*)d_in[4];
  const float* beta1  = (const float*)d_in[5];
  const float* W2     = (const float*)d_in[6];
  const float* b2     = (const float*)d_in[7];
  const float* W3     = (const float*)d_in[8];
  const float* b3     = (const float*)d_in[9];
  float* out = (float*)d_out;

  char* w = (char*)d_ws;
  float* buf0      = (float*)w; w += (size_t)NN*HN*4;   // hbf (25.6MB) + ebuf (12.9MB), disjoint
  float* buf1      = (float*)w; w += (size_t)NN*HN*4;   // abf bf16
  int*   csr_col   = (int*)w;   w += (size_t)EE*4;
  int*   row_start = (int*)w;   w += (size_t)NN*4;
  int*   cnt       = (int*)w;   w += (size_t)NN*4;
  float* dinv      = (float*)w; w += (size_t)NN*4;
  float* scale     = (float*)w; w += 1024;
  float* shiftv    = (float*)w; w += 1024;
  int*   scr0      = (int*)w;   w += 4096;   // pcur[256] | done | gps[128] | gpq[128]
  unsigned short* Wp2 = (unsigned short*)w; w += 128*128*2;
  unsigned short* Wp3 = (unsigned short*)w; w += 128*64*2;
  int*   pcur = scr0;                        // ints [0,256)
  int*   done = scr0 + 256;                  // int  [256]
  float* gps  = (float*)(scr0 + 320);        // floats [320,448)
  float* gpq  = (float*)(scr0 + 448);        // floats [448,576)
  unsigned* hbf  = (unsigned*)buf0;                 // bf16 h rows (64 uints/row), 25.6 MB
  unsigned* ebuf = (unsigned*)buf0 + (size_t)NN*64; // packed edge slabs, 12.9 MB (disjoint)
  unsigned* abf  = (unsigned*)buf1;                 // bf16 agg rows

  (void)hipMemsetAsync(scr0, 0, 4096, stream);      // zeroes pcur, done, gps, gpq

  const int AB = NN/4, FB = NN/16;

  // bucket || mgemm1 (independent) + W2/W3 pack
  k_fused<<<CB + GB, 256, 0, stream>>>(rows, cols, pcur, ebuf, x, W1, W2, W3, Wp2, Wp3, hbf);
  k_build<<<NBUCK, 256, 0, stream>>>(ebuf, pcur, row_start, cnt, dinv, csr_col);

  // layer 1: agg with per-edge dinv (+b1) -> abf; fused BN stats + finalize
  k_aggd<<<AB, 256, 0, stream>>>(hbf, row_start, cnt, csr_col, dinv, b1, abf);
  k_statsfin<<<SB, 256, 0, stream>>>(abf, gps, gpq, done, gamma1, beta1, scale, shiftv);

  // layer 2: BN+relu staged, @W2, pre-scaled bf16 h2'
  k_mgemm2<<<GB, 256, 0, stream>>>(abf, Wp2, scale, shiftv, dinv, hbf);

  // fused: agg2 + relu + GEMM3 + b3 -> out
  k_aggmm<<<FB, 256, 0, stream>>>(hbf, row_start, cnt, csr_col, dinv, b2, Wp3, b3, out);
}

// Round 15
// 239.814 us; speedup vs baseline: 1.0359x; 1.0359x over previous
//
#include <hip/hip_runtime.h>

#define NN 100000
#define EE 1600000
#define HN 128
#define OO 64
#define SB 256     // stats blocks
#define NBUCK 196  // ceil(NN/512), bucket = row >> 9
#define CH 4096    // edges per bucketing chunk
#define SLAB 16384 // fixed slab per bucket (mean 8192; overflow ~90 sigma -> nil)

typedef __attribute__((ext_vector_type(8))) short bf16x8;
typedef __attribute__((ext_vector_type(4))) float f32x4;

__device__ __forceinline__ unsigned short f2bf(float f){ // RNE bf16
  unsigned u = __float_as_uint(f);
  return (unsigned short)((u + 0x7FFFu + ((u >> 16) & 1u)) >> 16);
}
__device__ __forceinline__ float bflo(unsigned u){ return __uint_as_float(u << 16); }
__device__ __forceinline__ float bfhi(unsigned u){ return __uint_as_float(u & 0xFFFF0000u); }

#define CB ((EE + CH - 1)/CH)   // 391 bucket blocks
#define GB ((NN + 127)/128)     // 782 gemm blocks

// ---------------- fused: bucket-scatter (+W2/W3 pack) || mgemm1 (h1 = bf16(x@W1), UNSCALED) ----------------
__global__ __launch_bounds__(256) void k_fused(const int* __restrict__ rows, const int* __restrict__ cols,
                                               int* __restrict__ pcur, unsigned* __restrict__ ebuf,
                                               const float* __restrict__ x, const float* __restrict__ W1,
                                               const float* __restrict__ W2, const float* __restrict__ W3,
                                               unsigned short* __restrict__ Wp2, unsigned short* __restrict__ Wp3,
                                               unsigned* __restrict__ hbf){
  __shared__ char lds[65536];
  const int t = threadIdx.x;

  if (blockIdx.x < CB){
    // ================= bucket path =================
    int* bc    = (int*)lds;            // [256]
    int* boff  = (int*)(lds + 1024);
    int* ccur  = (int*)(lds + 2048);
    int* gbase = (int*)(lds + 3072);
    uint2* stage = (uint2*)(lds + 4096);  // 32 KB
    const int base = blockIdx.x * CH;
    const int nval = min(CH, EE - base);

    for (int i = t; i < NBUCK; i += 256) bc[i] = 0;
    __syncthreads();

    int er[16], ec[16];
    #pragma unroll
    for (int j = 0; j < 16; ++j){
      int i = j*256 + t;
      if (i < nval){
        er[j] = rows[base+i]; ec[j] = cols[base+i];
        atomicAdd(&bc[er[j] >> 9], 1);
      } else er[j] = -1;
    }
    __syncthreads();

    if (t < 64){ // wave-0 scan of bc -> boff
      int lane = t, run = 0;
      for (int c = 0; c < NBUCK; c += 64){
        int i = c + lane;
        int v = (i < NBUCK) ? bc[i] : 0;
        int s = v;
        #pragma unroll
        for (int d = 1; d < 64; d <<= 1){ int u = __shfl_up(s, d); if (lane >= d) s += u; }
        if (i < NBUCK) boff[i] = run + s - v;
        run += __shfl(s, 63);
      }
    }
    __syncthreads();
    if (t < NBUCK){
      gbase[t] = bc[t] ? (t*SLAB + atomicAdd(&pcur[t], bc[t])) : 0;
      ccur[t]  = boff[t];
    }
    __syncthreads();
    #pragma unroll
    for (int j = 0; j < 16; ++j){
      if (er[j] >= 0){
        int b = er[j] >> 9;
        int p = atomicAdd(&ccur[b], 1);
        stage[p] = make_uint2((unsigned)er[j], (unsigned)ec[j]);
      }
    }
    __syncthreads();
    for (int i = t; i < nval; i += 256){
      uint2 e = stage[i];
      int b = (int)(e.x >> 9);
      unsigned pk = ((e.x & 511u) << 17) | e.y;   // packed: lrow(9b) | col(17b)
      ebuf[gbase[b] + (i - boff[b])] = pk;
    }

    // W2/W3 pack on blocks 0..11 (consumed by later dispatches)
    int b = blockIdx.x;
    if (b < 12){
      const float* W = (b < 8) ? W2 : W3;
      unsigned short* Wp = (b < 8) ? Wp2 : Wp3;
      int outc = (b < 8) ? 128 : 64;
      int i0 = (b < 8) ? b*256 : (b-8)*256;
      int i = i0 + t;
      if (i < 16*outc){
        int kb = i / outc, n = i - kb*outc;
        unsigned pk[4];
        #pragma unroll
        for (int jj = 0; jj < 4; ++jj){
          unsigned lo = f2bf(W[(size_t)(kb*8 + 2*jj)*outc + n]);
          unsigned hi = f2bf(W[(size_t)(kb*8 + 2*jj+1)*outc + n]);
          pk[jj] = lo | (hi << 16);
        }
        *reinterpret_cast<uint4*>(Wp + (size_t)i*8) = make_uint4(pk[0],pk[1],pk[2],pk[3]);
      }
    }
  } else {
    // ================= mgemm1 path: h1 = bf16(x @ W1), unscaled =================
    char* AsB = lds;            // 32 KB A tile
    char* WsB = lds + 32768;    // 32 KB W tile [kb][n][8]
    const int row0 = (int)(blockIdx.x - CB) * 128;

    { // stage W1 fp32 -> bf16 packed (L2-hot after first block)
      #pragma unroll
      for (int it = 0; it < 8; ++it){
        int i = it*256 + t;            // 0..2047
        int kb = i >> 7, n = i & 127;
        unsigned pk[4];
        #pragma unroll
        for (int j = 0; j < 4; ++j){
          unsigned lo = f2bf(W1[(size_t)(kb*8 + 2*j)*128 + n]);
          unsigned hi = f2bf(W1[(size_t)(kb*8 + 2*j+1)*128 + n]);
          pk[j] = lo | (hi << 16);
        }
        *reinterpret_cast<uint4*>(WsB + (size_t)i*16) = make_uint4(pk[0],pk[1],pk[2],pk[3]);
      }
    }
    { // stage A (fp32 x) -> bf16 swizzled
      #pragma unroll
      for (int g = 0; g < 16; ++g){
        int f = g*256 + t;
        int r = f >> 5;
        int c4 = f & 31;
        int row = row0 + r;
        int rc = row < NN ? row : NN-1;
        float4 v = *reinterpret_cast<const float4*>(x + (size_t)rc*HN + c4*4);
        unsigned p0 = (unsigned)f2bf(v.x) | ((unsigned)f2bf(v.y) << 16);
        unsigned p1 = (unsigned)f2bf(v.z) | ((unsigned)f2bf(v.w) << 16);
        int boffb = (c4*8) ^ ((r & 7) << 4);
        *reinterpret_cast<uint2*>(AsB + r*256 + boffb) = make_uint2(p0, p1);
      }
    }
    __syncthreads();

    const int wv = t >> 6;
    const int l  = t & 63;
    const int lm = l & 15;
    const int lk = l >> 4;

    f32x4 acc[2][8];
    #pragma unroll
    for (int mi=0;mi<2;++mi)
      #pragma unroll
      for (int ni=0;ni<8;++ni) acc[mi][ni] = (f32x4){0.f,0.f,0.f,0.f};

    #pragma unroll
    for (int ks = 0; ks < 4; ++ks){
      bf16x8 af[2];
      #pragma unroll
      for (int mi=0;mi<2;++mi){
        int R = wv*32 + mi*16 + lm;
        int boffb = (ks*64 + lk*16) ^ ((R & 7) << 4);
        af[mi] = *reinterpret_cast<const bf16x8*>(AsB + R*256 + boffb);
      }
      int kb = ks*4 + lk;
      #pragma unroll
      for (int ni=0;ni<8;++ni){
        int n = ni*16 + lm;
        bf16x8 bfr = *reinterpret_cast<const bf16x8*>(WsB + (size_t)(kb*128 + n)*16);
        acc[0][ni] = __builtin_amdgcn_mfma_f32_16x16x32_bf16(af[0], bfr, acc[0][ni], 0,0,0);
        acc[1][ni] = __builtin_amdgcn_mfma_f32_16x16x32_bf16(af[1], bfr, acc[1][ni], 0,0,0);
      }
    }

    #pragma unroll
    for (int mi=0;mi<2;++mi){
      #pragma unroll
      for (int j=0;j<4;++j){
        int grow = row0 + wv*32 + mi*16 + lk*4 + j;
        if (grow >= NN) continue;
        unsigned short* po = (unsigned short*)hbf + (size_t)grow*HN;
        #pragma unroll
        for (int ni=0;ni<8;++ni)
          po[ni*16 + lm] = f2bf(acc[mi][ni][j]);   // UNSCALED
      }
    }
  }
}

// ---------------- per-bucket CSR finalize (slab, packed) ----------------
__global__ __launch_bounds__(256) void k_build(const unsigned* __restrict__ ebuf,
                                               const int* __restrict__ pcur,
                                               int* __restrict__ row_start, int* __restrict__ cnt,
                                               float* __restrict__ dinv, int* __restrict__ csr_col){
  __shared__ int hist[512];
  __shared__ int cur[512];
  __shared__ int sCbase;
  const int b = blockIdx.x;
  const int row0 = b << 9;
  const int nrow = min(512, NN - row0);
  const int ebase = b * SLAB;
  const int ne = pcur[b];
  const int t = threadIdx.x;

  if (t < 64){ // csr base = sum pcur[0..b)
    int acc = 0;
    for (int i = t; i < b; i += 64) acc += pcur[i];
    #pragma unroll
    for (int d = 32; d; d >>= 1) acc += __shfl_xor(acc, d);
    if (t == 0) sCbase = acc;
  }
  for (int i = t; i < nrow; i += 256) hist[i] = 0;
  __syncthreads();
  for (int i = t; i < ne; i += 256)
    atomicAdd(&hist[ebuf[ebase+i] >> 17], 1);
  __syncthreads();

  if (t < 64){
    int lane = t, run = 0;
    for (int c = 0; c < nrow; c += 64){
      int i = c + lane;
      int v = (i < nrow) ? hist[i] : 0;
      int s = v;
      #pragma unroll
      for (int d = 1; d < 64; d <<= 1){ int u = __shfl_up(s, d); if (lane >= d) s += u; }
      if (i < nrow) cur[i] = run + s - v;
      run += __shfl(s, 63);
    }
  }
  __syncthreads();
  const int cbase = sCbase;
  for (int i = t; i < nrow; i += 256){
    int h = hist[i];
    int r = row0 + i;
    cnt[r] = h;
    dinv[r] = rsqrtf((float)(h+1));
    row_start[r] = cbase + cur[i];
    cur[i] += cbase;
  }
  __syncthreads();
  for (int i = t; i < ne; i += 256){
    unsigned e = ebuf[ebase+i];
    int p = atomicAdd(&cur[e >> 17], 1);
    csr_col[p] = (int)(e & 0x1FFFFu);
  }
}

// ---------------- agg layer 1: dinv-weighted gather over UNSCALED bf16 h ----------------
__global__ __launch_bounds__(256) void k_aggd(const unsigned* __restrict__ h,
                                              const int* __restrict__ row_start,
                                              const int* __restrict__ cnt,
                                              const int* __restrict__ col,
                                              const float* __restrict__ dinv,
                                              const float* __restrict__ bias,
                                              unsigned* __restrict__ outv){
  int wib  = __builtin_amdgcn_readfirstlane((int)(threadIdx.x >> 6));
  int wid  = blockIdx.x*4 + wib;
  int lane = threadIdx.x & 63;
  if (wid >= NN) return;
  int s = row_start[wid];
  int e = s + cnt[wid];
  float dr = dinv[wid];
  const unsigned* hp = h + lane;
  float ax, ay;
  {
    unsigned u = hp[(size_t)wid*64];
    ax = dr*bflo(u); ay = dr*bfhi(u);
  }
  int p = s;
  for (; p+7 < e; p += 8){
    unsigned uu[8]; float dd[8];
    #pragma unroll
    for (int j=0;j<8;++j){ int c = col[p+j]; dd[j] = dinv[c]; uu[j] = hp[(size_t)c*64]; }
    #pragma unroll
    for (int j=0;j<8;++j){ ax = fmaf(bflo(uu[j]), dd[j], ax); ay = fmaf(bfhi(uu[j]), dd[j], ay); }
  }
  for (; p+3 < e; p += 4){
    unsigned uu[4]; float dd[4];
    #pragma unroll
    for (int j=0;j<4;++j){ int c = col[p+j]; dd[j] = dinv[c]; uu[j] = hp[(size_t)c*64]; }
    #pragma unroll
    for (int j=0;j<4;++j){ ax = fmaf(bflo(uu[j]), dd[j], ax); ay = fmaf(bfhi(uu[j]), dd[j], ay); }
  }
  for (; p < e; ++p){
    int c = col[p]; float d = dinv[c];
    unsigned u = hp[(size_t)c*64];
    ax = fmaf(bflo(u), d, ax); ay = fmaf(bfhi(u), d, ay);
  }
  float2 bb = *reinterpret_cast<const float2*>(bias + 2*lane);
  float ox = ax*dr + bb.x, oy = ay*dr + bb.y;
  outv[(size_t)wid*64 + lane] = (unsigned)f2bf(ox) | ((unsigned)f2bf(oy) << 16);
}

// ---------------- fused: agg layer-2 (pre-scaled h2') + relu + GEMM3 + b3 -> out fp32 ----------------
__global__ __launch_bounds__(256) void k_aggmm(const unsigned* __restrict__ h,
                                               const int* __restrict__ row_start,
                                               const int* __restrict__ cnt,
                                               const int* __restrict__ col,
                                               const float* __restrict__ dinv,
                                               const float* __restrict__ b2,
                                               const unsigned short* __restrict__ Wp3,
                                               const float* __restrict__ b3,
                                               float* __restrict__ out){
  __shared__ char AsB[32*256];   // 32 rows x 256 B bf16, XOR-swizzled
  const int t = threadIdx.x;
  const int wv = __builtin_amdgcn_readfirstlane(t >> 6);
  const int lane = t & 63;
  const int tile = blockIdx.x * 32;

  for (int k = 0; k < 8; ++k){
    int wid = tile + wv*8 + k;          // NN = 3125*32
    int s = row_start[wid];
    int e = s + cnt[wid];
    float dr = dinv[wid];
    const unsigned* hp = h + lane;
    float ax, ay;
    { unsigned u = hp[(size_t)wid*64]; ax = bflo(u); ay = bfhi(u); }
    int p = s;
    for (; p+7 < e; p += 8){
      unsigned uu[8];
      #pragma unroll
      for (int j=0;j<8;++j) uu[j] = hp[(size_t)col[p+j]*64];
      #pragma unroll
      for (int j=0;j<8;++j){ ax += bflo(uu[j]); ay += bfhi(uu[j]); }
    }
    for (; p+3 < e; p += 4){
      unsigned uu[4];
      #pragma unroll
      for (int j=0;j<4;++j) uu[j] = hp[(size_t)col[p+j]*64];
      #pragma unroll
      for (int j=0;j<4;++j){ ax += bflo(uu[j]); ay += bfhi(uu[j]); }
    }
    for (; p < e; ++p){
      unsigned u = hp[(size_t)col[p]*64];
      ax += bflo(u); ay += bfhi(u);
    }
    float2 bb = *reinterpret_cast<const float2*>(b2 + 2*lane);
    float ox = fmaxf(ax*dr + bb.x, 0.f);   // relu fused
    float oy = fmaxf(ay*dr + bb.y, 0.f);
    int r = wv*8 + k;
    unsigned pk = (unsigned)f2bf(ox) | ((unsigned)f2bf(oy) << 16);
    *reinterpret_cast<unsigned*>(AsB + r*256 + ((lane*4) ^ ((r & 7) << 4))) = pk;
  }
  __syncthreads();

  const int lm = lane & 15;
  const int lk = lane >> 4;
  const int mb  = wv >> 1;
  const int nb2 = (wv & 1) * 2;
  f32x4 acc[2] = {(f32x4){0.f,0.f,0.f,0.f},(f32x4){0.f,0.f,0.f,0.f}};
  const bf16x8* WpV = reinterpret_cast<const bf16x8*>(Wp3);

  #pragma unroll
  for (int ks = 0; ks < 4; ++ks){
    int R = mb*16 + lm;
    bf16x8 af = *reinterpret_cast<const bf16x8*>(AsB + R*256 + ((ks*64 + lk*16) ^ ((R & 7) << 4)));
    int kb = ks*4 + lk;
    #pragma unroll
    for (int ni = 0; ni < 2; ++ni){
      int n = (nb2+ni)*16 + lm;
      bf16x8 bfr = WpV[kb*OO + n];
      acc[ni] = __builtin_amdgcn_mfma_f32_16x16x32_bf16(af, bfr, acc[ni], 0,0,0);
    }
  }

  #pragma unroll
  for (int ni = 0; ni < 2; ++ni){
    int gcol = (nb2+ni)*16 + lm;
    float bb = b3[gcol];
    #pragma unroll
    for (int j = 0; j < 4; ++j){
      int grow = tile + mb*16 + lk*4 + j;
      out[(size_t)grow*OO + gcol] = acc[ni][j] + bb;
    }
  }
}

// ---------------- MFMA GEMM2: h2' = bf16(dinv * (BNrelu(abf) @ W2)) ----------------
__global__ __launch_bounds__(256) void k_mgemm2(const unsigned* __restrict__ Av,
                                                const unsigned short* __restrict__ Wp,
                                                const float* __restrict__ scale,
                                                const float* __restrict__ shiftv,
                                                const float* __restrict__ dinv,
                                                unsigned* __restrict__ Cv){
  __shared__ char AsB[32768];
  const int t = threadIdx.x;
  const int row0 = blockIdx.x * 128;

  { // stage bf16 A with BN+relu
    const uint4* A = (const uint4*)Av;   // 16 uint4 per row
    const int c8 = t & 15;
    const int k0 = c8*8;
    float sc[8], sh[8];
    #pragma unroll
    for (int j=0;j<8;++j){ sc[j]=scale[k0+j]; sh[j]=shiftv[k0+j]; }
    #pragma unroll
    for (int g = 0; g < 8; ++g){
      int f = g*256 + t;
      int r = f >> 4;
      int row = row0 + r;
      int rc = row < NN ? row : NN-1;
      uint4 q = A[(size_t)rc*16 + c8];
      float vf[8] = { bflo(q.x),bfhi(q.x),bflo(q.y),bfhi(q.y),
                      bflo(q.z),bfhi(q.z),bflo(q.w),bfhi(q.w) };
      #pragma unroll
      for (int j=0;j<8;++j) vf[j] = fmaxf(fmaf(vf[j], sc[j], sh[j]), 0.f);
      unsigned pk[4];
      #pragma unroll
      for (int j=0;j<4;++j)
        pk[j] = (unsigned)f2bf(vf[2*j]) | ((unsigned)f2bf(vf[2*j+1]) << 16);
      int boffb = (c8*16) ^ ((r & 7) << 4);
      *reinterpret_cast<uint4*>(AsB + r*256 + boffb) = make_uint4(pk[0],pk[1],pk[2],pk[3]);
    }
  }
  __syncthreads();

  const int wv = t >> 6;
  const int l  = t & 63;
  const int lm = l & 15;
  const int lk = l >> 4;

  f32x4 acc[2][8];
  #pragma unroll
  for (int mi=0;mi<2;++mi)
    #pragma unroll
    for (int ni=0;ni<8;++ni) acc[mi][ni] = (f32x4){0.f,0.f,0.f,0.f};

  const bf16x8* WpV = reinterpret_cast<const bf16x8*>(Wp);

  #pragma unroll
  for (int ks = 0; ks < 4; ++ks){
    bf16x8 af[2];
    #pragma unroll
    for (int mi=0;mi<2;++mi){
      int R = wv*32 + mi*16 + lm;
      int boffb = (ks*64 + lk*16) ^ ((R & 7) << 4);
      af[mi] = *reinterpret_cast<const bf16x8*>(AsB + R*256 + boffb);
    }
    int kb = ks*4 + lk;
    #pragma unroll
    for (int ni=0;ni<8;++ni){
      int n = ni*16 + lm;
      bf16x8 bfr = WpV[kb*128 + n];
      acc[0][ni] = __builtin_amdgcn_mfma_f32_16x16x32_bf16(af[0], bfr, acc[0][ni], 0,0,0);
      acc[1][ni] = __builtin_amdgcn_mfma_f32_16x16x32_bf16(af[1], bfr, acc[1][ni], 0,0,0);
    }
  }

  #pragma unroll
  for (int mi=0;mi<2;++mi){
    #pragma unroll
    for (int j=0;j<4;++j){
      int grow = row0 + wv*32 + mi*16 + lk*4 + j;
      if (grow >= NN) continue;
      float dr = dinv[grow];
      unsigned short* po = (unsigned short*)Cv + (size_t)grow*HN;
      #pragma unroll
      for (int ni=0;ni<8;++ni)
        po[ni*16 + lm] = f2bf(acc[mi][ni][j] * dr);
    }
  }
}

// ---------------- BN stats over bf16 rows (deterministic two-stage) ----------------
__global__ __launch_bounds__(256) void k_stats(const unsigned* __restrict__ a,
                                               float* __restrict__ ps, float* __restrict__ pq){
  __shared__ float l0[256], l1[256], m0[256], m1[256];
  int c = threadIdx.x & 63;
  int grp = threadIdx.x >> 6;
  float s0=0.f,s1=0.f,q0=0.f,q1=0.f;
  for (int r = blockIdx.x*4 + grp; r < NN; r += SB*4){
    unsigned u = a[(size_t)r*64 + c];
    float v0 = bflo(u), v1 = bfhi(u);
    s0 += v0; s1 += v1; q0 = fmaf(v0,v0,q0); q1 = fmaf(v1,v1,q1);
  }
  l0[threadIdx.x]=s0; l1[threadIdx.x]=s1; m0[threadIdx.x]=q0; m1[threadIdx.x]=q1;
  __syncthreads();
  if (grp==0){
    #pragma unroll
    for (int g=1;g<4;++g){ s0+=l0[g*64+c]; s1+=l1[g*64+c]; q0+=m0[g*64+c]; q1+=m1[g*64+c]; }
    ps[blockIdx.x*128 + 2*c]   = s0; ps[blockIdx.x*128 + 2*c+1] = s1;
    pq[blockIdx.x*128 + 2*c]   = q0; pq[blockIdx.x*128 + 2*c+1] = q1;
  }
}

__global__ __launch_bounds__(128) void k_bnfinal(const float* __restrict__ ps, const float* __restrict__ pq,
                                                 const float* __restrict__ gamma, const float* __restrict__ beta,
                                                 float* __restrict__ scale, float* __restrict__ shiftv){
  int c = threadIdx.x;
  float s=0.f, q=0.f;
  for (int b=0;b<SB;b++){ s += ps[b*128+c]; q += pq[b*128+c]; }
  float mean = s * (1.0f/NN);
  float var  = q * (1.0f/NN) - mean*mean;
  float inv  = rsqrtf(var + 1e-5f);
  float sc = gamma[c]*inv;
  scale[c]  = sc;
  shiftv[c] = beta[c] - mean*sc;
}

// ---------------- launch ----------------
extern "C" void kernel_launch(void* const* d_in, const int* in_sizes, int n_in,
                              void* d_out, int out_size, void* d_ws, size_t ws_size,
                              hipStream_t stream) {
  const float* x      = (const float*)d_in[0];
  const int*   ei     = (const int*)d_in[1];
  const int*   rows   = ei;
  const int*   cols   = ei + EE;
  const float* W1     = (const float*)d_in[2];
  const float* b1     = (const float*)d_in[3];
  const float* gamma1 = (const float*)d_in[4];
  const float* beta1  = (const float*)d_in[5];
  const float* W2     = (const float*)d_in[6];
  const float* b2     = (const float*)d_in[7];
  const float* W3     = (const float*)d_in[8];
  const float* b3     = (const float*)d_in[9];
  float* out = (float*)d_out;

  char* w = (char*)d_ws;
  float* buf0      = (float*)w; w += (size_t)NN*HN*4;   // hbf (25.6MB) + ebuf (12.9MB), disjoint
  float* buf1      = (float*)w; w += (size_t)NN*HN*4;   // abf bf16
  int*   csr_col   = (int*)w;   w += (size_t)EE*4;
  int*   row_start = (int*)w;   w += (size_t)NN*4;
  int*   cnt       = (int*)w;   w += (size_t)NN*4;
  float* dinv      = (float*)w; w += (size_t)NN*4;
  float* ps        = (float*)w; w += (size_t)SB*128*4;
  float* pq        = (float*)w; w += (size_t)SB*128*4;
  float* scale     = (float*)w; w += 1024;
  float* shiftv    = (float*)w; w += 1024;
  int*   scr0      = (int*)w;   w += 4096;   // pcur[256]
  unsigned short* Wp2 = (unsigned short*)w; w += 128*128*2;
  unsigned short* Wp3 = (unsigned short*)w; w += 128*64*2;
  int* pcur = scr0;
  unsigned* hbf  = (unsigned*)buf0;                 // bf16 h rows (64 uints/row), 25.6 MB
  unsigned* ebuf = (unsigned*)buf0 + (size_t)NN*64; // packed edge slabs, 12.9 MB (disjoint)
  unsigned* abf  = (unsigned*)buf1;                 // bf16 agg rows

  (void)hipMemsetAsync(scr0, 0, 4096, stream);

  const int AB = NN/4, FB = NN/32;

  // bucket || mgemm1 (independent) + W2/W3 pack
  k_fused<<<CB + GB, 256, 0, stream>>>(rows, cols, pcur, ebuf, x, W1, W2, W3, Wp2, Wp3, hbf);
  k_build<<<NBUCK, 256, 0, stream>>>(ebuf, pcur, row_start, cnt, dinv, csr_col);

  // layer 1: agg with per-edge dinv (+b1) -> abf; BN stats
  k_aggd<<<AB, 256, 0, stream>>>(hbf, row_start, cnt, csr_col, dinv, b1, abf);
  k_stats<<<SB, 256, 0, stream>>>(abf, ps, pq);
  k_bnfinal<<<1, 128, 0, stream>>>(ps, pq, gamma1, beta1, scale, shiftv);

  // layer 2: BN+relu staged, @W2, pre-scaled bf16 h2'
  k_mgemm2<<<GB, 256, 0, stream>>>(abf, Wp2, scale, shiftv, dinv, hbf);

  // fused: agg2 + relu + GEMM3 + b3 -> out
  k_aggmm<<<FB, 256, 0, stream>>>(hbf, row_start, cnt, csr_col, dinv, b2, Wp3, b3, out);
}